// Round 6
// baseline (3944.032 us; speedup 1.0000x reference)
//
#include <hip/hip_runtime.h>

// QINCo round 16: barrier-free m-owner restructure.
//  - k_step: 128-thread blocks (2 waves). Each wave owns 32 m-rows end-to-end.
//    H never goes to LDS: G1's C-fragments are repacked into G2's B-fragments
//    in-register via __shfl_xor(.,32) (col=m is the same lane for both GEMMs;
//    only the koct h-half crosses lanes).
//  - Z stays in LDS (32KB), but each wave touches only its own 32 rows ->
//    ZERO barriers in the main loop; one __syncthreads before dist.
//  - G1(ht) interleaved 1:1 with G2(ht-1): alternating acc chains restore
//    dep-distance 2. Per-accumulator MFMA order identical to R12/R15 ->
//    bit-identical numerics.
//  - Dist computed redundantly by both waves (same op order as before),
//    argmin fully in registers.
// Shapes: D=128, M=8, K=256, L=2, H=256, BS=1024.
// Out layout (floats): xhat[1024*128] | codes[1024*8] | side[8][1024*128]

typedef _Float16 f16;
typedef f16 half4_t __attribute__((ext_vector_type(4)));
typedef f16 half8_t __attribute__((ext_vector_type(8)));
typedef float f32x16 __attribute__((ext_vector_type(16)));

#define OUT_CODES 131072
#define OUT_SIDE  139264

// ws float offsets (unchanged)
#define WS_XHAT  0          // [1024][128]
#define WS_RB    131072     // [1024][128]  r = x - xhat
#define WS_Y     262144     // [1024][128]  y = xhat @ Wx^T
#define WS_ZC    393216     // [256][128]   zc = cb + cb@Wz^T + bc
#define WS_BESTD 425984     // [1024][4]
#define WS_BESTI 430080     // [1024][4] (int)
#define WS_BESTZ 434176     // [1024][4][128]
#define WS_WSPLIT 960000    // f16 region: W1H|W1L|W2H|W2L, NW1 halfs each
#define NW1 458752          // 7*2*256*128

#define ZLO 8192            // Zh -> Zl offset (halfs)

union H4I { half4_t h; int i[2]; };
union H8I { half8_t h; int i[4]; };

__device__ __forceinline__ f32x16 mfma_f16(half8_t a, half8_t b, f32x16 c) {
  return __builtin_amdgcn_mfma_f32_32x32x16_f16(a, b, c, 0, 0, 0);
}

// ---------------- weight pre-split: fp32 -> scaled (x256) fp16 hi/lo ----------------
__global__ __launch_bounds__(256) void k_wsplit(const float* __restrict__ W1,
    const float* __restrict__ W2, f16* __restrict__ wsh)
{
  int i = (blockIdx.x * 256 + threadIdx.x) * 4;      // [0, 2*NW1)
  const float* src;
  f16* hi;
  if (i < NW1) { src = W1 + i; hi = wsh + i; }
  else         { src = W2 + (i - NW1); hi = wsh + 2 * NW1 + (i - NW1); }
  f16* lo = hi + NW1;
  float4 v = *(const float4*)src;
  half4_t h, l;
  float s;
  s = v.x * 256.f; h[0] = (f16)s; l[0] = (f16)(s - (float)h[0]);
  s = v.y * 256.f; h[1] = (f16)s; l[1] = (f16)(s - (float)h[1]);
  s = v.z * 256.f; h[2] = (f16)s; l[2] = (f16)(s - (float)h[2]);
  s = v.w * 256.f; h[3] = (f16)s; l[3] = (f16)(s - (float)h[3]);
  *(half4_t*)hi = h;
  *(half4_t*)lo = l;
}

// ---------------- step 0: nearest codebook0 row ----------------
__global__ __launch_bounds__(256) void k_step0(const float* __restrict__ x,
    const float* __restrict__ cb0, float* __restrict__ ws, float* __restrict__ out)
{
  __shared__ float xs[128];
  __shared__ float redv[4];
  __shared__ int   redi[4];
  __shared__ int   kwin;
  int tx = threadIdx.x, b = blockIdx.x;
  if (tx < 128) xs[tx] = x[b * 128 + tx];
  __syncthreads();
  const float* c = cb0 + tx * 128;   // k = tx
  float s = 0.f;
  for (int d = 0; d < 128; d += 4) {
    float4 cv = *(const float4*)(c + d);
    float4 xv = *(const float4*)(xs + d);
    float a0 = xv.x - cv.x, a1 = xv.y - cv.y, a2 = xv.z - cv.z, a3 = xv.w - cv.w;
    s += a0 * a0 + a1 * a1 + a2 * a2 + a3 * a3;
  }
  float v = s; int idx = tx;
  for (int off = 32; off; off >>= 1) {
    float v2 = __shfl_xor(v, off);
    int   i2 = __shfl_xor(idx, off);
    if (v2 < v || (v2 == v && i2 < idx)) { v = v2; idx = i2; }
  }
  if ((tx & 63) == 0) { redv[tx >> 6] = v; redi[tx >> 6] = idx; }
  __syncthreads();
  if (tx == 0) {
    float bv = redv[0]; int bi = redi[0];
    for (int w = 1; w < 4; w++)
      if (redv[w] < bv || (redv[w] == bv && redi[w] < bi)) { bv = redv[w]; bi = redi[w]; }
    kwin = bi;
    out[OUT_CODES + b * 8] = (float)bi;
  }
  __syncthreads();
  int k = kwin;
  if (tx < 128) {
    float xh = cb0[k * 128 + tx];
    ws[WS_XHAT + b * 128 + tx] = xh;
    ws[WS_RB   + b * 128 + tx] = xs[tx] - xh;
    out[OUT_SIDE + b * 128 + tx] = xh;   // side[0]
  }
}

// ---------------- per-step prep: zc and y (fp32) ----------------
__global__ __launch_bounds__(128) void k_prep(const float* __restrict__ cb,
    const float* __restrict__ Wc, const float* __restrict__ bcm, float* __restrict__ ws)
{
  __shared__ float row[128];
  int tx = threadIdx.x, blk = blockIdx.x;
  if (blk < 256) {          // zc[k][i] = cb[k][i] + sum_d cb[k][d]*Wc[i][d] + bc[i]
    row[tx] = cb[blk * 128 + tx];
    __syncthreads();
    const float* wrow = Wc + tx * 256;
    float s = 0.f;
    for (int d = 0; d < 128; d += 4) {
      float4 wv = *(const float4*)(wrow + d);
      float4 zv = *(const float4*)(row + d);
      s += wv.x * zv.x + wv.y * zv.y + wv.z * zv.z + wv.w * zv.w;
    }
    ws[WS_ZC + blk * 128 + tx] = row[tx] + s + bcm[tx];
  } else {                  // y[b][i] = sum_d xhat[b][d]*Wc[i][128+d]
    int b = blk - 256;
    row[tx] = ws[WS_XHAT + b * 128 + tx];
    __syncthreads();
    const float* wrow = Wc + tx * 256 + 128;
    float s = 0.f;
    for (int d = 0; d < 128; d += 4) {
      float4 wv = *(const float4*)(wrow + d);
      float4 zv = *(const float4*)(row + d);
      s += wv.x * zv.x + wv.y * zv.y + wv.z * zv.z + wv.w * zv.w;
    }
    ws[WS_Y + b * 128 + tx] = s;
  }
}

// ---------------- main step kernel ----------------
// 128 threads = 2 waves. Wave w owns m-rows [32w, 32w+32).
// lane: col = lane&31 (= m_local = n-index of all MFMAs), koct = lane>>5.
// Z LDS rows 128 halfs; logical d of row m at phys (d + 8*(m&15)) & 127.
// Per layer, per h-tile ht (32 h):
//   [G1(ht) interleaved 1:1 with G2(ht-1)] -> issue a2(ht,dt0)+a1(ht+1) ->
//   pack acc1 -> hi/lo f16 -> shfl_xor(32) exchange -> G2 B-frags (pf*).
// After ht loop: G2(7) alone (dt-interleaved), then epilogue2 (Z += G2 out).
// C/D layout: col = N index; row = (reg&3)+8*(reg>>2)+4*koct.
__global__ __launch_bounds__(128, 2) void k_step(const f16* __restrict__ wsh,
    float* __restrict__ ws, int sm)
{
  __shared__ __align__(16) f16 lds[16384];     // 32 KB: Zh[64][128] | Zl
  f16* Zh = lds;
  f16* Zl = lds + ZLO;
  int tx = threadIdx.x;
  int lane = tx & 63, w = tx >> 6;
  int col = lane & 31, koct = lane >> 5;
  int b = blockIdx.x >> 2, t = blockIdx.x & 3, k0 = t << 6;

  // ---- init own 32 rows: Z = zc[k0+m] + y[b], split x256 (rotated store) ----
  {
    const float* zc = ws + WS_ZC + k0 * 128;
    const float* y  = ws + WS_Y + b * 128;
#pragma unroll
    for (int i = 0; i < 8; i++) {
      int idx = (i << 6) + lane;            // 0..511
      int m = (w << 5) + (idx & 31), d0 = (idx >> 5) << 3;
      float4 a  = *(const float4*)(zc + m * 128 + d0);
      float4 bb = *(const float4*)(zc + m * 128 + d0 + 4);
      float4 ya = *(const float4*)(y + d0);
      float4 yb = *(const float4*)(y + d0 + 4);
      float sv[8] = {a.x + ya.x, a.y + ya.y, a.z + ya.z, a.w + ya.w,
                     bb.x + yb.x, bb.y + yb.y, bb.z + yb.z, bb.w + yb.w};
      half8_t h8, l8;
#pragma unroll
      for (int j = 0; j < 8; j++) {
        float v = sv[j] * 256.f;
        f16 h = (f16)v; h8[j] = h; l8[j] = (f16)(v - (float)h);
      }
      int c0 = (d0 + ((m & 15) << 3)) & 127;
      *(half8_t*)(Zh + (m << 7) + c0) = h8;
      *(half8_t*)(Zl + (m << 7) + c0) = l8;
    }
  }
  // No barrier: until dist, each wave touches only its own rows.

  const int rot0 = (col & 15) << 3;
  const f16* Zr = Zh + (((w << 5) + col) << 7);   // own row m = 32w+col
  int poffs[8];
#pragma unroll
  for (int kc = 0; kc < 8; kc++)
    poffs[kc] = (((kc << 4) + (koct << 3)) + rot0) & 127;

  half8_t a1hv[8], a1lv[8];                // W1 A-frags, current h-tile
  half8_t ce0h, ce0l, ce1h, ce1l;          // W2 A-frags, current dt
  H8I pfeh, pfel, pfoh, pfol;              // H B-frags of previous h-tile

  for (int l = 0; l < 2; l++) {
    const f16* w1h = wsh + (size_t)((sm * 2 + l) * 256) * 128;
    const f16* w2h = wsh + 2 * NW1 + (size_t)((sm * 2 + l) * 128) * 256;
    f32x16 acc2[4];
#pragma unroll
    for (int dt = 0; dt < 4; dt++)
#pragma unroll
      for (int i = 0; i < 16; i++) acc2[dt][i] = 0.f;

    // a1 for ht=0 (rows h = col)
    {
      const f16* a1p = w1h + (size_t)col * 128 + (koct << 3);
#pragma unroll
      for (int kc = 0; kc < 8; kc++) {
        a1hv[kc] = *(const half8_t*)(a1p + (kc << 4));
        a1lv[kc] = *(const half8_t*)(a1p + NW1 + (kc << 4));
      }
    }

    for (int ht = 0; ht < 8; ht++) {
      f32x16 acc1;
#pragma unroll
      for (int i = 0; i < 16; i++) acc1[i] = 0.f;

      if (ht == 0) {
        // ---- G1(0) alone ----
        __builtin_amdgcn_s_setprio(1);
#pragma unroll
        for (int kc = 0; kc < 8; kc++) {
          half8_t bh = *(const half8_t*)(Zr + poffs[kc]);
          half8_t bl = *(const half8_t*)(Zr + ZLO + poffs[kc]);
          acc1 = mfma_f16(a1hv[kc], bh, acc1);
          acc1 = mfma_f16(a1lv[kc], bh, acc1);
          acc1 = mfma_f16(a1hv[kc], bl, acc1);
        }
        __builtin_amdgcn_s_setprio(0);
      } else {
        // ---- G1(ht) interleaved with G2(ht-1) ----
        const f16* a2b = w2h + (size_t)col * 256 + ((ht - 1) << 5) + (koct << 3);
        half8_t ne0h, ne0l, ne1h, ne1l;
        __builtin_amdgcn_s_setprio(1);
#pragma unroll
        for (int kc = 0; kc < 8; kc++) {
          const int dt = kc >> 1;
          half8_t bh = *(const half8_t*)(Zr + poffs[kc]);
          half8_t bl = *(const half8_t*)(Zr + ZLO + poffs[kc]);
          if ((kc & 1) == 0) {
            if (dt < 3) {                  // prefetch a2 for dt+1
              const f16* p = a2b + (size_t)(dt + 1) * 8192;
              ne0h = *(const half8_t*)(p);
              ne0l = *(const half8_t*)(p + NW1);
              ne1h = *(const half8_t*)(p + 16);
              ne1l = *(const half8_t*)(p + NW1 + 16);
            }
            acc1 = mfma_f16(a1hv[kc], bh, acc1);
            acc2[dt] = mfma_f16(ce0h, pfeh.h, acc2[dt]);
            acc1 = mfma_f16(a1lv[kc], bh, acc1);
            acc2[dt] = mfma_f16(ce0l, pfeh.h, acc2[dt]);
            acc1 = mfma_f16(a1hv[kc], bl, acc1);
            acc2[dt] = mfma_f16(ce0h, pfel.h, acc2[dt]);
          } else {
            acc1 = mfma_f16(a1hv[kc], bh, acc1);
            acc2[dt] = mfma_f16(ce1h, pfoh.h, acc2[dt]);
            acc1 = mfma_f16(a1lv[kc], bh, acc1);
            acc2[dt] = mfma_f16(ce1l, pfoh.h, acc2[dt]);
            acc1 = mfma_f16(a1hv[kc], bl, acc1);
            acc2[dt] = mfma_f16(ce1h, pfol.h, acc2[dt]);
            if (dt < 3) { ce0h = ne0h; ce0l = ne0l; ce1h = ne1h; ce1l = ne1l; }
          }
        }
        __builtin_amdgcn_s_setprio(0);
      }

      // ---- issue a2(ht, dt0) + a1(ht+1) loads (hidden under pack) ----
      {
        const f16* p = w2h + (size_t)col * 256 + (ht << 5) + (koct << 3);
        ce0h = *(const half8_t*)(p);
        ce0l = *(const half8_t*)(p + NW1);
        ce1h = *(const half8_t*)(p + 16);
        ce1l = *(const half8_t*)(p + NW1 + 16);
      }
      if (ht < 7) {
        const f16* a1p = w1h + (size_t)(((ht + 1) << 5) + col) * 128 + (koct << 3);
#pragma unroll
        for (int kc = 0; kc < 8; kc++) {
          a1hv[kc] = *(const half8_t*)(a1p + (kc << 4));
          a1lv[kc] = *(const half8_t*)(a1p + NW1 + (kc << 4));
        }
      }

      // ---- pack: relu, x2^-8, hi/lo split, shfl-exchange -> G2 B-frags ----
      {
        H4I qh[4], ql[4];
#pragma unroll
        for (int qd = 0; qd < 4; qd++) {
          half4_t hv, lv;
#pragma unroll
          for (int j = 0; j < 4; j++) {
            float tv = fmaxf(acc1[(qd << 2) + j], 0.f) * 0.00390625f;
            f16 hh = (f16)tv; hv[j] = hh; lv[j] = (f16)(tv - (float)hh);
          }
          qh[qd].h = hv; ql[qd].h = lv;
        }
        int xh[4][2], xl[4][2];
#pragma unroll
        for (int qd = 0; qd < 4; qd++) {
          xh[qd][0] = __shfl_xor(qh[qd].i[0], 32);
          xh[qd][1] = __shfl_xor(qh[qd].i[1], 32);
          xl[qd][0] = __shfl_xor(ql[qd].i[0], 32);
          xl[qd][1] = __shfl_xor(ql[qd].i[1], 32);
        }
        // frag element j must be H[m=col][h = base + koct*8 + j]:
        // even kc2 (h_local 0..15): lower = [self q0 | partner q0],
        //                           upper = [partner q1 | self q1]
        pfeh.i[0] = koct ? xh[1][0] : qh[0].i[0];
        pfeh.i[1] = koct ? xh[1][1] : qh[0].i[1];
        pfeh.i[2] = koct ? qh[1].i[0] : xh[0][0];
        pfeh.i[3] = koct ? qh[1].i[1] : xh[0][1];
        pfel.i[0] = koct ? xl[1][0] : ql[0].i[0];
        pfel.i[1] = koct ? xl[1][1] : ql[0].i[1];
        pfel.i[2] = koct ? ql[1].i[0] : xl[0][0];
        pfel.i[3] = koct ? ql[1].i[1] : xl[0][1];
        // odd kc2 (h_local 16..31): same with q2/q3
        pfoh.i[0] = koct ? xh[3][0] : qh[2].i[0];
        pfoh.i[1] = koct ? xh[3][1] : qh[2].i[1];
        pfoh.i[2] = koct ? qh[3].i[0] : xh[2][0];
        pfoh.i[3] = koct ? qh[3].i[1] : xh[2][1];
        pfol.i[0] = koct ? xl[3][0] : ql[2].i[0];
        pfol.i[1] = koct ? xl[3][1] : ql[2].i[1];
        pfol.i[2] = koct ? ql[3].i[0] : xl[2][0];
        pfol.i[3] = koct ? ql[3].i[1] : xl[2][1];
      }
    }

    // ---- G2(7) alone: dt-interleaved (dep distance 4) ----
    {
      const f16* a2b = w2h + (size_t)col * 256 + (7 << 5) + (koct << 3);
      half8_t d1e0h = *(const half8_t*)(a2b + 8192);
      half8_t d1e0l = *(const half8_t*)(a2b + 8192 + NW1);
      half8_t d1e1h = *(const half8_t*)(a2b + 8192 + 16);
      half8_t d1e1l = *(const half8_t*)(a2b + 8192 + NW1 + 16);
      half8_t d2e0h = *(const half8_t*)(a2b + 16384);
      half8_t d2e0l = *(const half8_t*)(a2b + 16384 + NW1);
      half8_t d2e1h = *(const half8_t*)(a2b + 16384 + 16);
      half8_t d2e1l = *(const half8_t*)(a2b + 16384 + NW1 + 16);
      half8_t d3e0h = *(const half8_t*)(a2b + 24576);
      half8_t d3e0l = *(const half8_t*)(a2b + 24576 + NW1);
      half8_t d3e1h = *(const half8_t*)(a2b + 24576 + 16);
      half8_t d3e1l = *(const half8_t*)(a2b + 24576 + NW1 + 16);
      __builtin_amdgcn_s_setprio(1);
#define G27(A0, A1, A2, A3, FR) \
      acc2[0] = mfma_f16(A0, FR, acc2[0]); \
      acc2[1] = mfma_f16(A1, FR, acc2[1]); \
      acc2[2] = mfma_f16(A2, FR, acc2[2]); \
      acc2[3] = mfma_f16(A3, FR, acc2[3]);
      G27(ce0h, d1e0h, d2e0h, d3e0h, pfeh.h)
      G27(ce0l, d1e0l, d2e0l, d3e0l, pfeh.h)
      G27(ce0h, d1e0h, d2e0h, d3e0h, pfel.h)
      G27(ce1h, d1e1h, d2e1h, d3e1h, pfoh.h)
      G27(ce1l, d1e1l, d2e1l, d3e1l, pfoh.h)
      G27(ce1h, d1e1h, d2e1h, d3e1h, pfol.h)
#undef G27
      __builtin_amdgcn_s_setprio(0);
    }

    // ---- epilogue2: Z[m=32w+col][d] += acc2 * 2^-8 (own rows only) ----
    {
      f16* zhr = Zh + (((w << 5) + col) << 7);
      f16* zlr = Zl + (((w << 5) + col) << 7);
#pragma unroll
      for (int dt = 0; dt < 4; dt++) {
#pragma unroll
        for (int qd = 0; qd < 4; qd++) {
          int c = (((dt << 5) + (qd << 3) + (koct << 2)) + rot0) & 127;
          half4_t zh = *(half4_t*)(zhr + c);
          half4_t zl = *(half4_t*)(zlr + c);
#pragma unroll
          for (int j = 0; j < 4; j++) {
            float zs = (float)zh[j] + (float)zl[j];
            zs += acc2[dt][(qd << 2) + j] * 0.00390625f;
            f16 hh = (f16)zs; zh[j] = hh; zl[j] = (f16)(zs - (float)hh);
          }
          *(half4_t*)(zhr + c) = zh;
          *(half4_t*)(zlr + c) = zl;
        }
      }
    }
    // no barrier: next layer's G1 reads only rows this wave wrote
  }

  __syncthreads();   // the only barrier: dist reads both waves' Z rows

  // ---- dist = ||rb - z||^2, all 64 rows, both waves redundantly ----
  float bv = 3.4e38f; int bi = 0;
  {
    int seg = lane & 3;
    const float* rb = ws + WS_RB + b * 128 + (seg << 5);
#pragma unroll
    for (int p = 0; p < 4; p++) {
      int row = (p << 4) + (lane >> 2);
      int rotr = (row & 15) << 3;
      const f16* zhr = Zh + (row << 7);
      const f16* zlr = Zl + (row << 7);
      float s = 0.f;
#pragma unroll
      for (int o = 0; o < 4; o++) {
        int c = (((seg << 5) + (o << 3)) + rotr) & 127;
        half8_t zh = *(const half8_t*)(zhr + c);
        half8_t zl = *(const half8_t*)(zlr + c);
        float4 r0 = *(const float4*)(rb + (o << 3));
        float4 r1 = *(const float4*)(rb + (o << 3) + 4);
        float rr[8] = {r0.x, r0.y, r0.z, r0.w, r1.x, r1.y, r1.z, r1.w};
#pragma unroll
        for (int j = 0; j < 8; j++) {
          float z = ((float)zh[j] + (float)zl[j]) * 0.00390625f;
          float dlt = rr[j] - z;
          s += dlt * dlt;
        }
      }
      s += __shfl_xor(s, 1);   // all 4 lanes of a row end bit-identical
      s += __shfl_xor(s, 2);
      if (seg == 0 && s < bv) { bv = s; bi = row; }  // rows ascending: strict <
    }
  }
#pragma unroll
  for (int off = 32; off; off >>= 1) {
    float v2 = __shfl_xor(bv, off);
    int   i2 = __shfl_xor(bi, off);
    if (v2 < bv || (v2 == bv && i2 < bi)) { bv = v2; bi = i2; }
  }
  if (tx == 0) {
    ws[WS_BESTD + (b << 2) + t] = bv;
    ((int*)ws)[WS_BESTI + (b << 2) + t] = k0 + bi;
  }
  if (tx < 32) {
    int rw = bi;
    int c = ((tx << 2) + ((rw & 15) << 3)) & 127;
    half4_t zh = *(const half4_t*)(Zh + (rw << 7) + c);
    half4_t zl = *(const half4_t*)(Zl + (rw << 7) + c);
    float4 z;
    z.x = ((float)zh[0] + (float)zl[0]) * 0.00390625f;
    z.y = ((float)zh[1] + (float)zl[1]) * 0.00390625f;
    z.z = ((float)zh[2] + (float)zl[2]) * 0.00390625f;
    z.w = ((float)zh[3] + (float)zl[3]) * 0.00390625f;
    *(float4*)(ws + WS_BESTZ + (((b << 2) + t) << 7) + (tx << 2)) = z;
  }
}

// ---------------- per-step update: pick tile winner, advance xhat ----------------
__global__ __launch_bounds__(128) void k_update(const float* __restrict__ x,
    float* __restrict__ ws, float* __restrict__ out, int m, int last)
{
  __shared__ int tsel;
  int tx = threadIdx.x, b = blockIdx.x;
  if (tx == 0) {
    float bv = ws[WS_BESTD + (b << 2)]; int bt = 0;
    for (int q = 1; q < 4; q++) {
      float v = ws[WS_BESTD + (b << 2) + q];
      if (v < bv) { bv = v; bt = q; }     // strict <: ties -> lowest k (tile order)
    }
    tsel = bt;
    int k = ((const int*)ws)[WS_BESTI + (b << 2) + bt];
    out[OUT_CODES + b * 8 + (m + 1)] = (float)k;
  }
  __syncthreads();
  int bt = tsel;
  float z  = ws[WS_BESTZ + (((b << 2) + bt) << 7) + tx];
  float xh = ws[WS_XHAT + b * 128 + tx] + z;
  ws[WS_XHAT + b * 128 + tx] = xh;
  ws[WS_RB   + b * 128 + tx] = x[b * 128 + tx] - xh;
  out[OUT_SIDE + (m + 1) * 131072 + b * 128 + tx] = xh;
  if (last) out[b * 128 + tx] = xh;       // final xhat == side[7]
}

extern "C" void kernel_launch(void* const* d_in, const int* in_sizes, int n_in,
                              void* d_out, int out_size, void* d_ws, size_t ws_size,
                              hipStream_t stream)
{
  const float* x   = (const float*)d_in[0];
  const float* cb0 = (const float*)d_in[1];
  const float* cbs = (const float*)d_in[2];
  const float* Wc  = (const float*)d_in[3];
  const float* bc  = (const float*)d_in[4];
  const float* W1  = (const float*)d_in[5];
  const float* W2  = (const float*)d_in[6];
  float* out = (float*)d_out;
  float* ws  = (float*)d_ws;
  f16* wsh = (f16*)(ws + WS_WSPLIT);

  k_wsplit<<<896, 256, 0, stream>>>(W1, W2, wsh);
  k_step0<<<1024, 256, 0, stream>>>(x, cb0, ws, out);
  for (int m = 0; m < 7; m++) {
    k_prep<<<1280, 128, 0, stream>>>(cbs + m * 256 * 128, Wc + m * 128 * 256,
                                     bc + m * 128, ws);
    k_step<<<4096, 128, 0, stream>>>(wsh, ws, m);
    k_update<<<1024, 128, 0, stream>>>(x, ws, out, m, (m == 6) ? 1 : 0);
  }
}

// Round 7
// 3573.454 us; speedup vs baseline: 1.1037x; 1.1037x over previous
//
#include <hip/hip_runtime.h>

// QINCo round 17: R13 kernel (verified correct) with the register budget it
// actually needs. R13's live set is the smallest of all variants (~130-140
// unified: 32 AGPR acc + 64 VGPR frags + temps) but was launched at
// __launch_bounds__(256,4) = 128-reg budget -> spilled (WRITE 121MB).
// This round: (256,3) = 170-reg budget -> fits with headroom; LDS 32KB ->
// 3 blocks/CU (12 waves/CU, 3 waves/SIMD vs R12's 2).
// Register-budget model (6 rounds of evidence): budget = 512/waves_per_SIMD
// unified (VGPR+AGPR); R12 uses 160 @2w, R13 needs ~140 -> fits @3w only.
// Shapes: D=128, M=8, K=256, L=2, H=256, BS=1024.
// Out layout (floats): xhat[1024*128] | codes[1024*8] | side[8][1024*128]

typedef _Float16 f16;
typedef f16 half4_t __attribute__((ext_vector_type(4)));
typedef f16 half8_t __attribute__((ext_vector_type(8)));
typedef float f32x16 __attribute__((ext_vector_type(16)));

#define OUT_CODES 131072
#define OUT_SIDE  139264

// ws float offsets (unchanged from R12)
#define WS_XHAT  0          // [1024][128]
#define WS_RB    131072     // [1024][128]  r = x - xhat
#define WS_Y     262144     // [1024][128]  y = xhat @ Wx^T
#define WS_ZC    393216     // [256][128]   zc = cb + cb@Wz^T + bc
#define WS_BESTD 425984     // [1024][4]
#define WS_BESTI 430080     // [1024][4] (int)
#define WS_BESTZ 434176     // [1024][4][128]
#define WS_WSPLIT 960000    // f16 region: W1H|W1L|W2H|W2L, NW1 halfs each
#define NW1 458752          // 7*2*256*128

#define HLO 4096            // hi->lo LDS offset (halfs), compile-time (32-row tiles)

__device__ __forceinline__ f32x16 mfma_f16(half8_t a, half8_t b, f32x16 c) {
  return __builtin_amdgcn_mfma_f32_32x32x16_f16(a, b, c, 0, 0, 0);
}

// ---------------- weight pre-split: fp32 -> scaled (x256) fp16 hi/lo ----------------
__global__ __launch_bounds__(256) void k_wsplit(const float* __restrict__ W1,
    const float* __restrict__ W2, f16* __restrict__ wsh)
{
  int i = (blockIdx.x * 256 + threadIdx.x) * 4;      // [0, 2*NW1)
  const float* src;
  f16* hi;
  if (i < NW1) { src = W1 + i; hi = wsh + i; }
  else         { src = W2 + (i - NW1); hi = wsh + 2 * NW1 + (i - NW1); }
  f16* lo = hi + NW1;
  float4 v = *(const float4*)src;
  half4_t h, l;
  float s;
  s = v.x * 256.f; h[0] = (f16)s; l[0] = (f16)(s - (float)h[0]);
  s = v.y * 256.f; h[1] = (f16)s; l[1] = (f16)(s - (float)h[1]);
  s = v.z * 256.f; h[2] = (f16)s; l[2] = (f16)(s - (float)h[2]);
  s = v.w * 256.f; h[3] = (f16)s; l[3] = (f16)(s - (float)h[3]);
  *(half4_t*)hi = h;
  *(half4_t*)lo = l;
}

// ---------------- step 0: nearest codebook0 row ----------------
__global__ __launch_bounds__(256) void k_step0(const float* __restrict__ x,
    const float* __restrict__ cb0, float* __restrict__ ws, float* __restrict__ out)
{
  __shared__ float xs[128];
  __shared__ float redv[4];
  __shared__ int   redi[4];
  __shared__ int   kwin;
  int tx = threadIdx.x, b = blockIdx.x;
  if (tx < 128) xs[tx] = x[b * 128 + tx];
  __syncthreads();
  const float* c = cb0 + tx * 128;   // k = tx
  float s = 0.f;
  for (int d = 0; d < 128; d += 4) {
    float4 cv = *(const float4*)(c + d);
    float4 xv = *(const float4*)(xs + d);
    float a0 = xv.x - cv.x, a1 = xv.y - cv.y, a2 = xv.z - cv.z, a3 = xv.w - cv.w;
    s += a0 * a0 + a1 * a1 + a2 * a2 + a3 * a3;
  }
  float v = s; int idx = tx;
  for (int off = 32; off; off >>= 1) {
    float v2 = __shfl_xor(v, off);
    int   i2 = __shfl_xor(idx, off);
    if (v2 < v || (v2 == v && i2 < idx)) { v = v2; idx = i2; }
  }
  if ((tx & 63) == 0) { redv[tx >> 6] = v; redi[tx >> 6] = idx; }
  __syncthreads();
  if (tx == 0) {
    float bv = redv[0]; int bi = redi[0];
    for (int w = 1; w < 4; w++)
      if (redv[w] < bv || (redv[w] == bv && redi[w] < bi)) { bv = redv[w]; bi = redi[w]; }
    kwin = bi;
    out[OUT_CODES + b * 8] = (float)bi;
  }
  __syncthreads();
  int k = kwin;
  if (tx < 128) {
    float xh = cb0[k * 128 + tx];
    ws[WS_XHAT + b * 128 + tx] = xh;
    ws[WS_RB   + b * 128 + tx] = xs[tx] - xh;
    out[OUT_SIDE + b * 128 + tx] = xh;   // side[0]
  }
}

// ---------------- per-step prep: zc and y (fp32) ----------------
__global__ __launch_bounds__(128) void k_prep(const float* __restrict__ cb,
    const float* __restrict__ Wc, const float* __restrict__ bcm, float* __restrict__ ws)
{
  __shared__ float row[128];
  int tx = threadIdx.x, blk = blockIdx.x;
  if (blk < 256) {          // zc[k][i] = cb[k][i] + sum_d cb[k][d]*Wc[i][d] + bc[i]
    row[tx] = cb[blk * 128 + tx];
    __syncthreads();
    const float* wrow = Wc + tx * 256;
    float s = 0.f;
    for (int d = 0; d < 128; d += 4) {
      float4 wv = *(const float4*)(wrow + d);
      float4 zv = *(const float4*)(row + d);
      s += wv.x * zv.x + wv.y * zv.y + wv.z * zv.z + wv.w * zv.w;
    }
    ws[WS_ZC + blk * 128 + tx] = row[tx] + s + bcm[tx];
  } else {                  // y[b][i] = sum_d xhat[b][d]*Wc[i][128+d]
    int b = blk - 256;
    row[tx] = ws[WS_XHAT + b * 128 + tx];
    __syncthreads();
    const float* wrow = Wc + tx * 256 + 128;
    float s = 0.f;
    for (int d = 0; d < 128; d += 4) {
      float4 wv = *(const float4*)(wrow + d);
      float4 zv = *(const float4*)(row + d);
      s += wv.x * zv.x + wv.y * zv.y + wv.z * zv.z + wv.w * zv.w;
    }
    ws[WS_Y + b * 128 + tx] = s;
  }
}

// ---------------- main step kernel ----------------
// 256 threads = 4 waves. lane: col = lane&31, koct = lane>>5.
// Two serial 32-row subtiles per block; LDS rows 128 halfs, 32 rows each of
// Zh/Zl/Hh/Hl (32KB total). Logical d of row m at phys (d + 8*(m&15)) & 127.
// Per subtile, per layer:
//   G1(hf0) | storeH0 | bar | G2(hf0) | loadA1(hf1) | G1(hf1) | bar |
//   storeH1 | bar | G2(hf1) | epi2 | bar
// C/D layout: col(lane&31) = N index (m); row = (reg&3)+8*(reg>>2)+4*koct.
__global__ __launch_bounds__(256, 3) void k_step(const f16* __restrict__ wsh,
    float* __restrict__ ws, int sm)
{
  __shared__ __align__(16) f16 lds[16384];     // 32 KB exactly
  f16* Zh = lds;            // [32][128]
  f16* Zl = lds + HLO;
  f16* Hh = lds + 2 * HLO;
  f16* Hl = lds + 3 * HLO;  // Hl - Hh == Zl - Zh == HLO by construction
  int tx = threadIdx.x;
  int lane = tx & 63, w = tx >> 6;
  int col = lane & 31, koct = lane >> 5;
  int b = blockIdx.x >> 2, t = blockIdx.x & 3, k0 = t << 6;

  const int rot0 = (col & 15) << 3;        // rotation for row col
  const f16* Zr0 = Zh + (col << 7);
  const f16* Hr0 = Hh + (col << 7);
  float* pd = (float*)Hh;                  // dist scratch (H dead by then)
  int* rwin = (int*)Hh + 64;

  float bestd = 3.4e38f;                   // meaningful in tx==0 only
  int   besti = 0;

  for (int st = 0; st < 2; st++) {
    int kb = k0 + (st << 5);

    // ---- init Z = zc[kb+m] + y[b], split x256 into Zh/Zl (rotated store) ----
    {
      const float* zc = ws + WS_ZC + kb * 128;
      const float* y  = ws + WS_Y + b * 128;
      for (int idx = tx; idx < 512; idx += 256) {
        int m = idx & 31, d0 = (idx >> 5) << 3;
        float4 a  = *(const float4*)(zc + m * 128 + d0);
        float4 bb = *(const float4*)(zc + m * 128 + d0 + 4);
        float4 ya = *(const float4*)(y + d0);
        float4 yb = *(const float4*)(y + d0 + 4);
        float sv[8] = {a.x + ya.x, a.y + ya.y, a.z + ya.z, a.w + ya.w,
                       bb.x + yb.x, bb.y + yb.y, bb.z + yb.z, bb.w + yb.w};
        half8_t h8, l8;
#pragma unroll
        for (int j = 0; j < 8; j++) {
          float v = sv[j] * 256.f;
          f16 h = (f16)v; h8[j] = h; l8[j] = (f16)(v - (float)h);
        }
        int c0 = (d0 + ((m & 15) << 3)) & 127;
        *(half8_t*)(Zh + (m << 7) + c0) = h8;
        *(half8_t*)(Zl + (m << 7) + c0) = l8;
      }
    }
    __syncthreads();

    for (int l = 0; l < 2; l++) {
      const f16* w1h = wsh + (size_t)((sm * 2 + l) * 256) * 128;
      const f16* w2h = wsh + 2 * NW1 + (size_t)((sm * 2 + l) * 128) * 256;
      f32x16 acc2;
#pragma unroll
      for (int i = 0; i < 16; i++) acc2[i] = 0.f;

      // ================= hf 0 =================
      half8_t a1hv[8], a1lv[8];
      {
        const f16* a1p = w1h + (size_t)((w << 5) + col) * 128 + (koct << 3);
#pragma unroll
        for (int kc = 0; kc < 8; kc++) {
          a1hv[kc] = *(const half8_t*)(a1p + (kc << 4));
          a1lv[kc] = *(const half8_t*)(a1p + NW1 + (kc << 4));
        }
      }
      f32x16 acc1;
#pragma unroll
      for (int i = 0; i < 16; i++) acc1[i] = 0.f;
      __builtin_amdgcn_s_setprio(1);
#pragma unroll
      for (int kc = 0; kc < 8; kc++) {
        int poff = (((kc << 4) + (koct << 3)) + rot0) & 127;
        half8_t bh0 = *(const half8_t*)(Zr0 + poff);
        half8_t bl0 = *(const half8_t*)(Zr0 + HLO + poff);
        acc1 = mfma_f16(a1hv[kc], bh0, acc1);
        acc1 = mfma_f16(a1lv[kc], bh0, acc1);
        acc1 = mfma_f16(a1hv[kc], bl0, acc1);
      }
      __builtin_amdgcn_s_setprio(0);

      // a2(hf0) loads: hide under epilogue + barrier
      half8_t a2hv[8], a2lv[8];
      {
        const f16* a2p = w2h + (size_t)((w << 5) + col) * 256 + (koct << 3);
#pragma unroll
        for (int kc = 0; kc < 8; kc++) {
          a2hv[kc] = *(const half8_t*)(a2p + (kc << 4));
          a2lv[kc] = *(const half8_t*)(a2p + NW1 + (kc << 4));
        }
      }

      // epilogue1: relu, rescale (x 2^-8), split, store H(hf0) at row m=col
#pragma unroll
      for (int qd = 0; qd < 4; qd++) {
        half4_t hv, lv;
#pragma unroll
        for (int j = 0; j < 4; j++) {
          float tv = fmaxf(acc1[(qd << 2) + j], 0.f) * 0.00390625f;
          f16 h = (f16)tv; hv[j] = h; lv[j] = (f16)(tv - (float)h);
        }
        int c = (((w << 5) + (qd << 3) + (koct << 2)) + rot0) & 127;
        *(half4_t*)(Hh + (col << 7) + c) = hv;
        *(half4_t*)(Hl + (col << 7) + c) = lv;
      }
      __syncthreads();                       // H(hf0) visible to all waves

      // GEMM2(hf0): reads H(hf0)
      __builtin_amdgcn_s_setprio(1);
#pragma unroll
      for (int kc = 0; kc < 8; kc++) {
        int poff = (((kc << 4) + (koct << 3)) + rot0) & 127;
        half8_t bh0 = *(const half8_t*)(Hr0 + poff);
        half8_t bl0 = *(const half8_t*)(Hr0 + HLO + poff);
        acc2 = mfma_f16(a2hv[kc], bh0, acc2);
        acc2 = mfma_f16(a2lv[kc], bh0, acc2);
        acc2 = mfma_f16(a2hv[kc], bl0, acc2);
      }
      __builtin_amdgcn_s_setprio(0);
      // NO barrier here: the hazard (H overwrite) is at storeH(hf1) below.

      // ================= hf 1 =================
      {
        const f16* a1p = w1h + (size_t)(128 + (w << 5) + col) * 128 + (koct << 3);
#pragma unroll
        for (int kc = 0; kc < 8; kc++) {
          a1hv[kc] = *(const half8_t*)(a1p + (kc << 4));
          a1lv[kc] = *(const half8_t*)(a1p + NW1 + (kc << 4));
        }
      }
#pragma unroll
      for (int i = 0; i < 16; i++) acc1[i] = 0.f;
      __builtin_amdgcn_s_setprio(1);
#pragma unroll
      for (int kc = 0; kc < 8; kc++) {
        int poff = (((kc << 4) + (koct << 3)) + rot0) & 127;
        half8_t bh0 = *(const half8_t*)(Zr0 + poff);
        half8_t bl0 = *(const half8_t*)(Zr0 + HLO + poff);
        acc1 = mfma_f16(a1hv[kc], bh0, acc1);
        acc1 = mfma_f16(a1lv[kc], bh0, acc1);
        acc1 = mfma_f16(a1hv[kc], bl0, acc1);
      }
      __builtin_amdgcn_s_setprio(0);

      // a2(hf1) loads: hide under the two barriers + epilogue below
      {
        const f16* a2q = w2h + (size_t)((w << 5) + col) * 256 + 128 + (koct << 3);
#pragma unroll
        for (int kc = 0; kc < 8; kc++) {
          a2hv[kc] = *(const half8_t*)(a2q + (kc << 4));
          a2lv[kc] = *(const half8_t*)(a2q + NW1 + (kc << 4));
        }
      }
      __syncthreads();                       // all waves done READING H(hf0)

      // epilogue1: store H(hf1)
#pragma unroll
      for (int qd = 0; qd < 4; qd++) {
        half4_t hv, lv;
#pragma unroll
        for (int j = 0; j < 4; j++) {
          float tv = fmaxf(acc1[(qd << 2) + j], 0.f) * 0.00390625f;
          f16 h = (f16)tv; hv[j] = h; lv[j] = (f16)(tv - (float)h);
        }
        int c = (((w << 5) + (qd << 3) + (koct << 2)) + rot0) & 127;
        *(half4_t*)(Hh + (col << 7) + c) = hv;
        *(half4_t*)(Hl + (col << 7) + c) = lv;
      }
      __syncthreads();                       // H(hf1) visible

      // GEMM2(hf1)
      __builtin_amdgcn_s_setprio(1);
#pragma unroll
      for (int kc = 0; kc < 8; kc++) {
        int poff = (((kc << 4) + (koct << 3)) + rot0) & 127;
        half8_t bh0 = *(const half8_t*)(Hr0 + poff);
        half8_t bl0 = *(const half8_t*)(Hr0 + HLO + poff);
        acc2 = mfma_f16(a2hv[kc], bh0, acc2);
        acc2 = mfma_f16(a2lv[kc], bh0, acc2);
        acc2 = mfma_f16(a2hv[kc], bl0, acc2);
      }
      __builtin_amdgcn_s_setprio(0);

      // epilogue2: Z[m=col][32w + d_local] += acc2 * 2^-8 (scaled units)
      {
        f16* zhr = Zh + (col << 7);
        f16* zlr = Zl + (col << 7);
#pragma unroll
        for (int qd = 0; qd < 4; qd++) {
          int c = (((w << 5) + (qd << 3) + (koct << 2)) + rot0) & 127;
          half4_t zh = *(half4_t*)(zhr + c);
          half4_t zl = *(half4_t*)(zlr + c);
#pragma unroll
          for (int j = 0; j < 4; j++) {
            float zs = (float)zh[j] + (float)zl[j];
            zs += acc2[(qd << 2) + j] * 0.00390625f;
            f16 h = (f16)zs; zh[j] = h; zl[j] = (f16)(zs - (float)h);
          }
          *(half4_t*)(zhr + c) = zh;
          *(half4_t*)(zlr + c) = zl;
        }
      }
      __syncthreads();                       // Z visible (next layer / dist)
    }

    // ---- dist = ||rb - z||^2 over 32 rows (4 threads/row, 32 d each) ----
    if (tx < 128) {
      int row = tx >> 2, seg = tx & 3;
      int rotr = (row & 15) << 3;
      const f16* zhr = Zh + (row << 7);
      const f16* zlr = Zl + (row << 7);
      const float* rb = ws + WS_RB + b * 128 + (seg << 5);
      float s = 0.f;
#pragma unroll
      for (int o = 0; o < 4; o++) {
        int c = (((seg << 5) + (o << 3)) + rotr) & 127;
        half8_t zh = *(const half8_t*)(zhr + c);
        half8_t zl = *(const half8_t*)(zlr + c);
        float4 r0 = *(const float4*)(rb + (o << 3));
        float4 r1 = *(const float4*)(rb + (o << 3) + 4);
        float rr[8] = {r0.x, r0.y, r0.z, r0.w, r1.x, r1.y, r1.z, r1.w};
#pragma unroll
        for (int j = 0; j < 8; j++) {
          float z = ((float)zh[j] + (float)zl[j]) * 0.00390625f;
          float dlt = rr[j] - z;
          s += dlt * dlt;
        }
      }
      s += __shfl_xor(s, 1);   // all 4 lanes of a row end bit-identical
      s += __shfl_xor(s, 2);
      if (seg == 0) pd[row] = s;
    }
    __syncthreads();
    if (tx < 32) {
      float v = pd[tx]; int idx = tx;
#pragma unroll
      for (int off = 16; off; off >>= 1) {
        float v2 = __shfl_xor(v, off);
        int   i2 = __shfl_xor(idx, off);
        if (v2 < v || (v2 == v && i2 < idx)) { v = v2; idx = i2; }
      }
      if (tx == 0) {
        int better = (v < bestd) ? 1 : 0;    // strict <: ties -> lower k (st order)
        if (better) { bestd = v; besti = kb + idx; rwin[0] = idx; }
        rwin[1] = better;
      }
    }
    __syncthreads();
    if (rwin[1] && tx < 32) {
      int rw = rwin[0];
      int c = ((tx << 2) + ((rw & 15) << 3)) & 127;
      half4_t zh = *(const half4_t*)(Zh + (rw << 7) + c);
      half4_t zl = *(const half4_t*)(Zl + (rw << 7) + c);
      float4 z;
      z.x = ((float)zh[0] + (float)zl[0]) * 0.00390625f;
      z.y = ((float)zh[1] + (float)zl[1]) * 0.00390625f;
      z.z = ((float)zh[2] + (float)zl[2]) * 0.00390625f;
      z.w = ((float)zh[3] + (float)zl[3]) * 0.00390625f;
      *(float4*)(ws + WS_BESTZ + (((b << 2) + t) << 7) + (tx << 2)) = z;
    }
    __syncthreads();   // BESTZ read of Z done before next subtile's init overwrites
  }

  if (tx == 0) {
    ws[WS_BESTD + (b << 2) + t] = bestd;
    ((int*)ws)[WS_BESTI + (b << 2) + t] = besti;
  }
}

// ---------------- per-step update: pick tile winner, advance xhat ----------------
__global__ __launch_bounds__(128) void k_update(const float* __restrict__ x,
    float* __restrict__ ws, float* __restrict__ out, int m, int last)
{
  __shared__ int tsel;
  int tx = threadIdx.x, b = blockIdx.x;
  if (tx == 0) {
    float bv = ws[WS_BESTD + (b << 2)]; int bt = 0;
    for (int q = 1; q < 4; q++) {
      float v = ws[WS_BESTD + (b << 2) + q];
      if (v < bv) { bv = v; bt = q; }     // strict <: ties -> lowest k (tile order)
    }
    tsel = bt;
    int k = ((const int*)ws)[WS_BESTI + (b << 2) + bt];
    out[OUT_CODES + b * 8 + (m + 1)] = (float)k;
  }
  __syncthreads();
  int bt = tsel;
  float z  = ws[WS_BESTZ + (((b << 2) + bt) << 7) + tx];
  float xh = ws[WS_XHAT + b * 128 + tx] + z;
  ws[WS_XHAT + b * 128 + tx] = xh;
  ws[WS_RB   + b * 128 + tx] = x[b * 128 + tx] - xh;
  out[OUT_SIDE + (m + 1) * 131072 + b * 128 + tx] = xh;
  if (last) out[b * 128 + tx] = xh;       // final xhat == side[7]
}

extern "C" void kernel_launch(void* const* d_in, const int* in_sizes, int n_in,
                              void* d_out, int out_size, void* d_ws, size_t ws_size,
                              hipStream_t stream)
{
  const float* x   = (const float*)d_in[0];
  const float* cb0 = (const float*)d_in[1];
  const float* cbs = (const float*)d_in[2];
  const float* Wc  = (const float*)d_in[3];
  const float* bc  = (const float*)d_in[4];
  const float* W1  = (const float*)d_in[5];
  const float* W2  = (const float*)d_in[6];
  float* out = (float*)d_out;
  float* ws  = (float*)d_ws;
  f16* wsh = (f16*)(ws + WS_WSPLIT);

  k_wsplit<<<896, 256, 0, stream>>>(W1, W2, wsh);
  k_step0<<<1024, 256, 0, stream>>>(x, cb0, ws, out);
  for (int m = 0; m < 7; m++) {
    k_prep<<<1280, 128, 0, stream>>>(cbs + m * 256 * 128, Wc + m * 128 * 256,
                                     bc + m * 128, ws);
    k_step<<<4096, 256, 0, stream>>>(wsh, ws, m);
    k_update<<<1024, 128, 0, stream>>>(x, ws, out, m, (m == 6) ? 1 : 0);
  }
}